// Round 1
// baseline (582.522 us; speedup 1.0000x reference)
//
#include <hip/hip_runtime.h>

#define C_DIM 768

// d_ws layout:
//   [0)       8 x uint counts
//   [1024)    WaT4: granule (k4, o) -> float4 {Wa[o][4k4..4k4+3]}, g = k4*192 + o
//             o in [0,168): Wa rows (a*56+e*8+r); o in [168,175): w_gate col e; else 0
//   [590848)  WbT4: granule (o, c4) -> float4 {WbT[o][4c4..+3]}, g = o*192 + c4, o = a*56+k

__global__ __launch_bounds__(256) void transpose_wa(
    const float* __restrict__ wa, const float* __restrict__ wg,
    float4* __restrict__ waT4) {
  const int g = blockIdx.x * 256 + threadIdx.x;   // 192*192 = 36864
  const int o = g % 192, k4 = g / 192;
  float4 v = make_float4(0.f, 0.f, 0.f, 0.f);
  if (o < 168) {
    v = *(const float4*)(wa + (size_t)o * C_DIM + k4 * 4);
  } else if (o < 175) {
    const int e = o - 168;
    v.x = wg[(k4 * 4 + 0) * 7 + e];
    v.y = wg[(k4 * 4 + 1) * 7 + e];
    v.z = wg[(k4 * 4 + 2) * 7 + e];
    v.w = wg[(k4 * 4 + 3) * 7 + e];
  }
  waT4[g] = v;
}

__global__ __launch_bounds__(256) void transpose_wb(
    const float* __restrict__ wb, float4* __restrict__ wbT4) {
  const int g = blockIdx.x * 256 + threadIdx.x;   // 168*192 = 32256
  const int c4 = g % 192, ak = g / 192;
  const int a = ak / 56, k = ak - a * 56;
  const int e = k >> 3, r = k & 7;
  const float* s = wb + ((size_t)(a * 7 + e) * C_DIM + c4 * 4) * 8 + r;
  wbT4[g] = make_float4(s[0], s[8], s[16], s[24]);
}

// 16 tokens per block, 4 per wave: grid = T/16 = 1024 blocks -> 4 blocks/CU,
// 16 waves/CU (4 waves/SIMD) vs the previous 2/SIMD grid-limited occupancy.
__global__ __launch_bounds__(256, 4) void moe_main(
    const float* __restrict__ x, const float4* __restrict__ waT4,
    const float4* __restrict__ wbT4, float* __restrict__ out,
    unsigned int* __restrict__ counts, int T) {
  __shared__ float xs[4][2][4][64];   // per-wave double-buffered x chunk (8 KB)
  __shared__ float hsT[168][20];      // h^T [o][tok], stride 20 (16B-aligned cols)

  const int tid = threadIdx.x;
  const int w = tid >> 6, lane = tid & 63;
  const int half = lane >> 5, l5 = lane & 31;
  const int t0 = blockIdx.x * 16;
  const int tb = w * 4;

  // ---------------- Stage 1: h = x @ WaT (+ gating logits) ----------------
  // lane-half token split: half h owns tokens [h*2, h*2+2); lane covers
  // o = l5 + 32m, m=0..5 (o in 0..191; rows >=175 are zero-padded).
  float acc1[2][6];
  #pragma unroll
  for (int tl = 0; tl < 2; ++tl)
    #pragma unroll
    for (int m = 0; m < 6; ++m) acc1[tl][m] = 0.f;

  const int xt = lane >> 4, xc = (lane & 15) * 4;
  const float* xbase = x + (size_t)(t0 + tb + xt) * C_DIM + xc;
  const float4* wa_l = waT4 + l5;

  // warmup: chunk 0 staged, chunk 1 in regs, weight steps 0,1 in flight
  float4 xr = *(const float4*)(xbase);
  *(float4*)&xs[w][0][xt][xc] = xr;
  xr = *(const float4*)(xbase + 64);

  float4 wv[2][6];
  #pragma unroll
  for (int m = 0; m < 6; ++m) wv[0][m] = wa_l[32 * m];
  #pragma unroll
  for (int m = 0; m < 6; ++m) wv[1][m] = wa_l[192 + 32 * m];

  #pragma unroll 1
  for (int ch = 0; ch < 12; ++ch) {
    // hand next chunk to LDS, issue load for chunk+2
    if (ch < 11) {
      *(float4*)&xs[w][(ch + 1) & 1][xt][xc] = xr;
      if (ch < 10) {
        xr = *(const float4*)(xbase + (ch + 2) * 64);
      }
    }
    const int buf = ch & 1;
    #pragma unroll
    for (int kk = 0; kk < 16; ++kk) {
      const int p = kk & 1;   // (ch*16+kk)&1 == kk&1 since 16 is even
      float4 xv[2];
      #pragma unroll
      for (int tl = 0; tl < 2; ++tl)
        xv[tl] = *(const float4*)&xs[w][buf][half * 2 + tl][kk * 4];
      #pragma unroll
      for (int m = 0; m < 6; ++m) {
        const float4 wvv = wv[p][m];
        #pragma unroll
        for (int tl = 0; tl < 2; ++tl) {
          float s = acc1[tl][m];
          s = fmaf(xv[tl].x, wvv.x, s);
          s = fmaf(xv[tl].y, wvv.y, s);
          s = fmaf(xv[tl].z, wvv.z, s);
          s = fmaf(xv[tl].w, wvv.w, s);
          acc1[tl][m] = s;
        }
      }
      // prefetch weights for step+2 into the buffer just consumed (clamped tail)
      int gn = ch * 16 + kk + 2;
      gn = gn > 191 ? 191 : gn;
      #pragma unroll
      for (int m = 0; m < 6; ++m) wv[p][m] = wa_l[(size_t)gn * 192 + 32 * m];
    }
  }

  // ---- argmax over logits (o=168+e -> m=5, l5=8+e, same half), counts ----
  int be[2];
  #pragma unroll
  for (int tl = 0; tl < 2; ++tl) {
    float best = __shfl(acc1[tl][5], (lane & 32) + 8);
    int b = 0;
    #pragma unroll
    for (int e = 1; e < 7; ++e) {
      const float lv = __shfl(acc1[tl][5], (lane & 32) + 8 + e);
      if (lv > best) { best = lv; b = e; }   // strict > = lowest-index tie-break
    }
    be[tl] = b;
  }
  if (l5 == 0) {
    #pragma unroll
    for (int tl = 0; tl < 2; ++tl) atomicAdd(&counts[be[tl]], 1u);
  }

  // ---- scale by hierarchy coefficient, write h^T (same-wave consumer) ----
  #pragma unroll
  for (int tl = 0; tl < 2; ++tl) {
    const int b = be[tl];
    const int tcol = tb + half * 2 + tl;
    #pragma unroll
    for (int m = 0; m < 6; ++m) {
      const int o = l5 + 32 * m;
      if (o < 168) {
        const int e = (o % 56) >> 3;
        float co = (e == b) ? 1.f : 0.f;
        if (b >= 4 && e < 4) co += 0.25f;
        if (b == 6 && (e == 4 || e == 5)) co += 0.5f;
        hsT[o][tcol] = acc1[tl][m] * co;
      }
    }
  }
  // no __syncthreads: each wave reads only its own hsT columns below

  // ---------------- Stage 2: y[a] = h[a] @ WbT[a] ----------------
  const float4* wb_l = wbT4 + lane;
  float4 u[2][3], hb[2];
  #pragma unroll
  for (int cc = 0; cc < 3; ++cc) {
    u[0][cc] = wb_l[64 * cc];
    u[1][cc] = wb_l[192 + 64 * cc];
  }
  hb[0] = *(const float4*)&hsT[0][tb];
  hb[1] = *(const float4*)&hsT[1][tb];

  #pragma unroll 1
  for (int a = 0; a < 3; ++a) {
    float4 acc2[3][4];
    #pragma unroll
    for (int cc = 0; cc < 3; ++cc)
      #pragma unroll
      for (int t = 0; t < 4; ++t) acc2[cc][t] = make_float4(0.f, 0.f, 0.f, 0.f);

    #pragma unroll 4
    for (int kq = 0; kq < 56; ++kq) {
      const int o = a * 56 + kq;
      const int p = kq & 1;   // (a*56+kq)&1 == kq&1 since 56 is even
      const float hv[4] = {hb[p].x, hb[p].y, hb[p].z, hb[p].w};
      const float4 w0 = u[p][0], w1 = u[p][1], w2 = u[p][2];
      #pragma unroll
      for (int t = 0; t < 4; ++t) {
        const float s = hv[t];
        acc2[0][t].x = fmaf(w0.x, s, acc2[0][t].x);
        acc2[0][t].y = fmaf(w0.y, s, acc2[0][t].y);
        acc2[0][t].z = fmaf(w0.z, s, acc2[0][t].z);
        acc2[0][t].w = fmaf(w0.w, s, acc2[0][t].w);
        acc2[1][t].x = fmaf(w1.x, s, acc2[1][t].x);
        acc2[1][t].y = fmaf(w1.y, s, acc2[1][t].y);
        acc2[1][t].z = fmaf(w1.z, s, acc2[1][t].z);
        acc2[1][t].w = fmaf(w1.w, s, acc2[1][t].w);
        acc2[2][t].x = fmaf(w2.x, s, acc2[2][t].x);
        acc2[2][t].y = fmaf(w2.y, s, acc2[2][t].y);
        acc2[2][t].z = fmaf(w2.z, s, acc2[2][t].z);
        acc2[2][t].w = fmaf(w2.w, s, acc2[2][t].w);
      }
      // prefetch o+2 into just-consumed buffers (clamped tail; row 167 re-read)
      int on = o + 2;
      on = on > 167 ? 167 : on;
      #pragma unroll
      for (int cc = 0; cc < 3; ++cc) u[p][cc] = wb_l[(size_t)on * 192 + 64 * cc];
      hb[p] = *(const float4*)&hsT[on][tb];
    }

    #pragma unroll
    for (int cc = 0; cc < 3; ++cc)
      #pragma unroll
      for (int t = 0; t < 4; ++t)
        *(float4*)(out + ((size_t)a * T + t0 + tb + t) * C_DIM + cc * 256 + lane * 4)
            = acc2[cc][t];
  }
}

// loss = 2 * cv2(counts)  (importance == load == counts when K=1, gate==1.0)
__global__ void loss_k(const unsigned int* __restrict__ counts,
                       float* __restrict__ out, int T) {
  if (threadIdx.x == 0) {
    float c[7], mean = 0.f;
    #pragma unroll
    for (int e = 0; e < 7; ++e) { c[e] = (float)counts[e]; mean += c[e]; }
    mean *= (1.f / 7.f);
    float var = 0.f;
    #pragma unroll
    for (int e = 0; e < 7; ++e) { const float d = c[e] - mean; var += d * d; }
    var *= (1.f / 6.f);  // ddof=1
    out[(size_t)3 * T * C_DIM] = 2.f * (var / (mean * mean + 1e-10f));
  }
}

extern "C" void kernel_launch(void* const* d_in, const int* in_sizes, int n_in,
                              void* d_out, int out_size, void* d_ws, size_t ws_size,
                              hipStream_t stream) {
  const float* x  = (const float*)d_in[0];
  const float* wg = (const float*)d_in[1];
  const float* Wa = (const float*)d_in[2];
  const float* Wb = (const float*)d_in[3];
  float* out = (float*)d_out;

  unsigned int* counts = (unsigned int*)d_ws;
  float4* waT4 = (float4*)((char*)d_ws + 1024);
  float4* wbT4 = (float4*)((char*)d_ws + 590848);

  const int T = in_sizes[0] / C_DIM;  // 16384

  hipMemsetAsync(counts, 0, 8 * sizeof(unsigned int), stream);
  transpose_wa<<<dim3(144), dim3(256), 0, stream>>>(Wa, wg, waT4);
  transpose_wb<<<dim3(126), dim3(256), 0, stream>>>(Wb, wbT4);
  moe_main<<<dim3(T / 16), dim3(256), 0, stream>>>(x, waT4, wbT4, out, counts, T);
  loss_k<<<dim3(1), dim3(64), 0, stream>>>(counts, out, T);
}

// Round 2
// 466.550 us; speedup vs baseline: 1.2486x; 1.2486x over previous
//
#include <hip/hip_runtime.h>

#define C_DIM 768

// d_ws layout:
//   [0)       8 x uint counts
//   [1024)    WaT4: granule (k4, o) -> float4 {Wa[o][4k4..4k4+3]}, g = k4*192 + o
//             o in [0,168): Wa rows (a*56+e*8+r); o in [168,175): w_gate col e; else 0
//   [590848)  WbT4: granule (o, c4) -> float4 {WbT[o][4c4..+3]}, g = o*192 + c4, o = a*56+k

__global__ __launch_bounds__(256) void transpose_w(
    const float* __restrict__ wa, const float* __restrict__ wg,
    const float* __restrict__ wb,
    float4* __restrict__ waT4, float4* __restrict__ wbT4) {
  const int b = blockIdx.x;
  if (b < 144) {
    const int g = b * 256 + threadIdx.x;   // 192*192 = 36864
    const int o = g % 192, k4 = g / 192;
    float4 v = make_float4(0.f, 0.f, 0.f, 0.f);
    if (o < 168) {
      v = *(const float4*)(wa + (size_t)o * C_DIM + k4 * 4);
    } else if (o < 175) {
      const int e = o - 168;
      v.x = wg[(k4 * 4 + 0) * 7 + e];
      v.y = wg[(k4 * 4 + 1) * 7 + e];
      v.z = wg[(k4 * 4 + 2) * 7 + e];
      v.w = wg[(k4 * 4 + 3) * 7 + e];
    }
    waT4[g] = v;
  } else {
    const int g = (b - 144) * 256 + threadIdx.x;   // 168*192 = 32256 exactly
    const int c4 = g % 192, ak = g / 192;
    const int a = ak / 56, k = ak - a * 56;
    const int e = k >> 3, r = k & 7;
    const float* s = wb + ((size_t)(a * 7 + e) * C_DIM + c4 * 4) * 8 + r;
    wbT4[g] = make_float4(s[0], s[8], s[16], s[24]);
  }
}

// 9-wave (576-thread) blocks, 16 tokens each; grid = T/16 = 1024 -> 2 blocks/CU
// = 18 waves/CU = 4.5 waves/SIMD. Output dims split across waves so weight
// streams are amortized per-block, not per-wave:
//   stage 1: wave = (o-chunk 64) x (k-third 256), lane = o-row   [3x3 = 9]
//   stage 2: wave = (a) x (c-third 256), lane = c-granule        [3x3 = 9]
// __launch_bounds__(576,5): VGPR cap 512/5 = 102 (stage-2 peak ~95) -> avoids
// both spills and the >102-VGPR cliff to 1 block/CU.
__global__ __launch_bounds__(576, 5) void moe_main(
    const float* __restrict__ x, const float4* __restrict__ waT4,
    const float4* __restrict__ wbT4, float* __restrict__ out,
    unsigned int* __restrict__ counts, int T) {
  __shared__ float4 xs4[16 * 192];   // 48 KB: x[t][k4], linear granules
  __shared__ float4 hsT4[192 * 4];   // 12 KB: h[o][t0..15], 4 granules/row
  __shared__ int bes[16];

  const int tid = threadIdx.x;
  const int w = tid / 64, lane = tid % 64;
  const int t0 = blockIdx.x * 16;
  float* hs = (float*)hsT4;

  // ---- stage x (linear copy: xs4[g] = x4[t0*192 + g]) + zero hsT ----
  const float4* x4 = (const float4*)x;
  for (int g = tid; g < 3072; g += 576) xs4[g] = x4[(size_t)t0 * 192 + g];
  for (int g = tid; g < 768; g += 576) hsT4[g] = make_float4(0.f, 0.f, 0.f, 0.f);
  __syncthreads();

  // ---------------- Stage 1: partial h = x @ WaT over this wave's k-third ----
  const int oi = w / 3, ki = w % 3;
  const int o1 = oi * 64 + lane;                       // output row (0..191)
  float acc[16];
  #pragma unroll
  for (int t = 0; t < 16; ++t) acc[t] = 0.f;

  const float4* wa_p = waT4 + (size_t)(ki * 64) * 192 + o1;  // + s*192 per step
  const float4* xk = xs4 + ki * 64;                          // xs4[t*192 + ki*64 + s]
  float4 wv0 = wa_p[0];
  float4 wv1 = wa_p[192];

  #pragma unroll 2
  for (int s = 0; s < 64; ++s) {
    const float4 wv = (s & 1) ? wv1 : wv0;
    int sn = s + 2; sn = sn > 63 ? 63 : sn;            // prefetch s+2 (clamped)
    if (s & 1) wv1 = wa_p[(size_t)sn * 192];
    else       wv0 = wa_p[(size_t)sn * 192];
    #pragma unroll
    for (int t = 0; t < 16; ++t) {
      const float4 xv = xk[t * 192 + s];               // uniform broadcast read
      float v = acc[t];
      v = fmaf(xv.x, wv.x, v);
      v = fmaf(xv.y, wv.y, v);
      v = fmaf(xv.z, wv.z, v);
      v = fmaf(xv.w, wv.w, v);
      acc[t] = v;
    }
  }

  // reduce the 3 k-partials: LDS float atomics, t-order permuted per lane so
  // banks (17*lane + j pattern) spread instead of 16-way colliding.
  #pragma unroll
  for (int j = 0; j < 16; ++j) {
    const int t = (lane + j) & 15;
    atomicAdd(hs + o1 * 16 + t, acc[t]);
  }
  __syncthreads();

  // ---- argmax over logits rows 168..174 (wave 0, lane = token) ----
  if (w == 0 && lane < 16) {
    const int t = lane;
    float best = hs[168 * 16 + t];
    int b = 0;
    #pragma unroll
    for (int e = 1; e < 7; ++e) {
      const float lv = hs[(168 + e) * 16 + t];
      if (lv > best) { best = lv; b = e; }             // strict > = lowest-index tie-break
    }
    bes[t] = b;
    atomicAdd(&counts[b], 1u);
  }
  __syncthreads();

  // ---- scale h rows by hierarchy coefficient ----
  for (int g = tid; g < 168 * 16; g += 576) {
    const int o = g >> 4, t = g & 15;
    const int e = (o % 56) >> 3, b = bes[t];
    float co = (e == b) ? 1.f : 0.f;
    if (b >= 4 && e < 4) co += 0.25f;
    if (b == 6 && (e == 4 || e == 5)) co += 0.5f;
    hs[g] *= co;
  }
  __syncthreads();

  // ---------------- Stage 2: y[a][t][c-third] = h[a] @ WbT[a] ----------------
  const int a = w / 3, ci = w % 3;
  const float4* wb_p = wbT4 + (size_t)(a * 56) * 192 + ci * 64 + lane;  // + k*192
  const float4* hrow = hsT4 + (size_t)(a * 56) * 4;                     // + k*4

  float4 acc2[16];
  #pragma unroll
  for (int t = 0; t < 16; ++t) acc2[t] = make_float4(0.f, 0.f, 0.f, 0.f);

  float4 u0 = wb_p[0];
  float4 u1 = wb_p[192];

  #pragma unroll 2
  for (int k = 0; k < 56; ++k) {
    const float4 u = (k & 1) ? u1 : u0;
    int kn = k + 2; kn = kn > 55 ? 55 : kn;            // prefetch k+2 (clamped)
    if (k & 1) u1 = wb_p[(size_t)kn * 192];
    else       u0 = wb_p[(size_t)kn * 192];
    #pragma unroll
    for (int q = 0; q < 4; ++q) {
      const float4 hq = hrow[k * 4 + q];               // uniform broadcast read
      const float hh[4] = {hq.x, hq.y, hq.z, hq.w};
      #pragma unroll
      for (int j = 0; j < 4; ++j) {
        const float s = hh[j];
        float4 A = acc2[q * 4 + j];
        A.x = fmaf(u.x, s, A.x);
        A.y = fmaf(u.y, s, A.y);
        A.z = fmaf(u.z, s, A.z);
        A.w = fmaf(u.w, s, A.w);
        acc2[q * 4 + j] = A;
      }
    }
  }

  float4* out4 = (float4*)out;
  const size_t obase = ((size_t)a * T + t0) * 192 + ci * 64 + lane;
  #pragma unroll
  for (int t = 0; t < 16; ++t) out4[obase + (size_t)t * 192] = acc2[t];
}

// loss = 2 * cv2(counts)  (importance == load == counts when K=1, gate==1.0)
__global__ void loss_k(const unsigned int* __restrict__ counts,
                       float* __restrict__ out, int T) {
  if (threadIdx.x == 0) {
    float c[7], mean = 0.f;
    #pragma unroll
    for (int e = 0; e < 7; ++e) { c[e] = (float)counts[e]; mean += c[e]; }
    mean *= (1.f / 7.f);
    float var = 0.f;
    #pragma unroll
    for (int e = 0; e < 7; ++e) { const float d = c[e] - mean; var += d * d; }
    var *= (1.f / 6.f);  // ddof=1
    out[(size_t)3 * T * C_DIM] = 2.f * (var / (mean * mean + 1e-10f));
  }
}

extern "C" void kernel_launch(void* const* d_in, const int* in_sizes, int n_in,
                              void* d_out, int out_size, void* d_ws, size_t ws_size,
                              hipStream_t stream) {
  const float* x  = (const float*)d_in[0];
  const float* wg = (const float*)d_in[1];
  const float* Wa = (const float*)d_in[2];
  const float* Wb = (const float*)d_in[3];
  float* out = (float*)d_out;

  unsigned int* counts = (unsigned int*)d_ws;
  float4* waT4 = (float4*)((char*)d_ws + 1024);
  float4* wbT4 = (float4*)((char*)d_ws + 590848);

  const int T = in_sizes[0] / C_DIM;  // 16384

  hipMemsetAsync(counts, 0, 8 * sizeof(unsigned int), stream);
  transpose_w<<<dim3(270), dim3(256), 0, stream>>>(Wa, wg, Wb, waT4, wbT4);
  moe_main<<<dim3(T / 16), dim3(576), 0, stream>>>(x, waT4, wbT4, out, counts, T);
  loss_k<<<dim3(1), dim3(64), 0, stream>>>(counts, out, T);
}